// Round 7
// baseline (718.642 us; speedup 1.0000x reference)
//
#include <hip/hip_runtime.h>
#include <hip/hip_bf16.h>
#include <stdint.h>

// CrossAttention (B=4, N=M=4096, C=512), fp32 in/out, bf16 MFMA internally.
// Round 7: register-direct GEMMs — no LDS staging, no K-loop barriers.
// Each lane global_load_dwordx4's its own MFMA fragment (16-B contiguous)
// into a 2-deep register ring; per-register vmcnt gives free-running waves
// (the LDS+barrier structure drained vmcnt(0) every iter — latency cap).
//   Q    = rgb @ WqT^T (+bq)          [16384 x 512]        rd_gemm 128x128
//   K    = dep @ WkT^T (+bk)          [16384 x 512]        rd_gemm
//   Vt   = WvT @ dep^T (+bv row)      per batch [512x4096] rd_gemm
//   expS = exp(Q K^T / sqrt(C))       per batch [4096^2]   rd_gemm OUT=EXP
//   O    = (expS @ Vt^T) / rowsum     per batch [4096x512] rd_pv 64x256

typedef unsigned short u16;
typedef __attribute__((ext_vector_type(8))) short bf16x8;
typedef __attribute__((ext_vector_type(16))) float f32x16;
typedef __attribute__((ext_vector_type(4))) unsigned short u16x4;

__device__ __forceinline__ u16 f2bf(float f) {  // RNE f32 -> bf16
  unsigned x = __float_as_uint(f);
  return (u16)((x + 0x7fffu + ((x >> 16) & 1u)) >> 16);
}
__device__ __forceinline__ float bf2f(short s) {
  return __uint_as_float((unsigned)(unsigned short)s << 16);
}

// ---------------------------------------------------------------------------
// Register-direct GEMM: C[M,N] = A[M,K]*B[N,K]^T, bf16 in, fp32 acc.
// 256 thr / 4 waves (2x2), block tile 128x128, wave tile 64x64, BK=32.
// Fragment loads: lane (ln31, half) reads A[row][k0+kc*16+half*8 ..+8) --
// exactly the 32x32x16 A/B operand layout -- as global_load_dwordx4 into a
// 2-deep register ring. No LDS, no barriers; latency hidden by 3 waves/SIMD
// free-running (launch_bounds(256,3)) + depth-2 pipeline.
// OUT_MODE: 0 bf16, 1 fp32, 2 bf16 of exp(v*scale). BIAS: 0/1(col)/2(row).
// ---------------------------------------------------------------------------
template <int BIAS_MODE, int OUT_MODE>
__global__ __launch_bounds__(256, 3) void rd_gemm(
    const u16* __restrict__ A, const u16* __restrict__ Bm,
    const float* __restrict__ bias, void* __restrict__ Cv, int M, int N, int K,
    long long sAb, long long sBb, long long sCb, float scale) {
  const int bz = blockIdx.z;
  A += (size_t)bz * sAb;
  Bm += (size_t)bz * sBb;
  const int bm = blockIdx.y * 128;
  const int bn = blockIdx.x * 128;
  const int tid = threadIdx.x;
  const int wave = tid >> 6, lane = tid & 63;
  const int ln31 = lane & 31, half = lane >> 5;
  const int wr = wave >> 1, wc = wave & 1;

  const u16* ap[2];
  const u16* bp[2];
#pragma unroll
  for (int mt = 0; mt < 2; ++mt)
    ap[mt] = A + (size_t)(bm + wr * 64 + mt * 32 + ln31) * K + half * 8;
#pragma unroll
  for (int nt = 0; nt < 2; ++nt)
    bp[nt] = Bm + (size_t)(bn + wc * 64 + nt * 32 + ln31) * K + half * 8;

  bf16x8 la[2][2][2], lb[2][2][2];  // [buf][mt|nt][kc]
  f32x16 acc[2][2] = {};

  auto load = [&](int buf) {
#pragma unroll
    for (int mt = 0; mt < 2; ++mt) {
#pragma unroll
      for (int kc = 0; kc < 2; ++kc)
        la[buf][mt][kc] = *(const bf16x8*)(ap[mt] + kc * 16);
      ap[mt] += 32;
    }
#pragma unroll
    for (int nt = 0; nt < 2; ++nt) {
#pragma unroll
      for (int kc = 0; kc < 2; ++kc)
        lb[buf][nt][kc] = *(const bf16x8*)(bp[nt] + kc * 16);
      bp[nt] += 32;
    }
  };
  auto compute = [&](int buf) {
#pragma unroll
    for (int kc = 0; kc < 2; ++kc)
#pragma unroll
      for (int mt = 0; mt < 2; ++mt)
#pragma unroll
        for (int nt = 0; nt < 2; ++nt)
          acc[mt][nt] = __builtin_amdgcn_mfma_f32_32x32x16_bf16(
              la[buf][mt][kc], lb[buf][nt][kc], acc[mt][nt], 0, 0, 0);
  };

  const int niter = K >> 5;  // 16 or 128 here: even, >= 4
  load(0);
  load(1);
  for (int it = 0; it < niter - 2; it += 2) {
    compute(0);
    load(0);
    compute(1);
    load(1);
  }
  compute(0);
  compute(1);

  // Epilogue. 32x32 C/D layout: col = lane&31, row = (r&3)+8*(r>>2)+4*half.
  const int crow0 = bm + wr * 64 + 4 * half;
  const int ccol0 = bn + wc * 64 + ln31;
#pragma unroll
  for (int mt = 0; mt < 2; ++mt) {
#pragma unroll
    for (int nt = 0; nt < 2; ++nt) {
      const int col = ccol0 + nt * 32;
#pragma unroll
      for (int r = 0; r < 16; ++r) {
        const int row = crow0 + mt * 32 + (r & 3) + 8 * (r >> 2);
        float v = acc[mt][nt][r];
        if constexpr (BIAS_MODE == 1) v += bias[col];
        if constexpr (BIAS_MODE == 2) v += bias[row];
        const size_t idx = (size_t)bz * (size_t)sCb + (size_t)row * N + col;
        if constexpr (OUT_MODE == 0)
          ((u16*)Cv)[idx] = f2bf(v);
        else if constexpr (OUT_MODE == 1)
          ((float*)Cv)[idx] = v;
        else
          ((u16*)Cv)[idx] = f2bf(__expf(v * scale));
      }
    }
  }
}

// ---------------------------------------------------------------------------
// Register-direct PV: O[64 q x 256 d] = (expS_slab @ Vt^T) / rowsum(expS).
// 4 waves along d (wave tile 64x64); all waves share the same 64 q-rows, so
// den = register rowsum of the A fragments (no atomics). One barrier AFTER
// the K-loop to publish den via 256-B LDS. grid (2,64,4).
// ---------------------------------------------------------------------------
__global__ __launch_bounds__(256, 3) void rd_pv(const u16* __restrict__ P,
                                                const u16* __restrict__ Vt,
                                                float* __restrict__ O) {
  const int bz = blockIdx.z;
  const u16* A = P + (size_t)bz * (4096ull * 4096ull);
  const u16* B = Vt + (size_t)bz * (512ull * 4096ull);
  float* Ob = O + (size_t)bz * (4096ull * 512ull);

  const int bm = blockIdx.y * 64;   // q slab
  const int bn = blockIdx.x * 256;  // d half

  __shared__ float den_s[64];

  const int tid = threadIdx.x;
  const int wave = tid >> 6, lane = tid & 63;
  const int ln31 = lane & 31, half = lane >> 5;

  const u16* ap[2];
  const u16* bp[2];
#pragma unroll
  for (int mt = 0; mt < 2; ++mt)
    ap[mt] = A + (size_t)(bm + mt * 32 + ln31) * 4096 + half * 8;
#pragma unroll
  for (int nt = 0; nt < 2; ++nt)
    bp[nt] = B + (size_t)(bn + wave * 64 + nt * 32 + ln31) * 4096 + half * 8;

  bf16x8 la[2][2][2], lb[2][2][2];
  f32x16 acc[2][2] = {};
  float rsum[2] = {0.f, 0.f};

  auto load = [&](int buf) {
#pragma unroll
    for (int mt = 0; mt < 2; ++mt) {
#pragma unroll
      for (int kc = 0; kc < 2; ++kc)
        la[buf][mt][kc] = *(const bf16x8*)(ap[mt] + kc * 16);
      ap[mt] += 32;
    }
#pragma unroll
    for (int nt = 0; nt < 2; ++nt) {
#pragma unroll
      for (int kc = 0; kc < 2; ++kc)
        lb[buf][nt][kc] = *(const bf16x8*)(bp[nt] + kc * 16);
      bp[nt] += 32;
    }
  };
  auto compute = [&](int buf) {
#pragma unroll
    for (int kc = 0; kc < 2; ++kc) {
#pragma unroll
      for (int mt = 0; mt < 2; ++mt) {
#pragma unroll
        for (int j = 0; j < 8; ++j) rsum[mt] += bf2f(la[buf][mt][kc][j]);
#pragma unroll
        for (int nt = 0; nt < 2; ++nt)
          acc[mt][nt] = __builtin_amdgcn_mfma_f32_32x32x16_bf16(
              la[buf][mt][kc], lb[buf][nt][kc], acc[mt][nt], 0, 0, 0);
      }
    }
  };

  load(0);
  load(1);
  for (int it = 0; it < 126; it += 2) {  // niter = 128
    compute(0);
    load(0);
    compute(1);
    load(1);
  }
  compute(0);
  compute(1);

  // den: lane (ln31, half) summed k = kc*16+half*8+j over all iters for rows
  // mt*32+ln31; combine the two k-halves, then wave 0 publishes.
#pragma unroll
  for (int mt = 0; mt < 2; ++mt) rsum[mt] += __shfl_xor(rsum[mt], 32, 64);
  if (wave == 0 && half == 0) {
    den_s[ln31] = rsum[0];
    den_s[32 + ln31] = rsum[1];
  }
  __syncthreads();

  const int crow0 = 4 * half;
  const int ccol0 = bn + wave * 64 + ln31;
#pragma unroll
  for (int mt = 0; mt < 2; ++mt) {
#pragma unroll
    for (int r = 0; r < 16; ++r) {
      const int rl = crow0 + mt * 32 + (r & 3) + 8 * (r >> 2);
      const float rd = 1.0f / den_s[rl];
#pragma unroll
      for (int nt = 0; nt < 2; ++nt)
        Ob[(size_t)(bm + rl) * 512 + ccol0 + nt * 32] = acc[mt][nt][r] * rd;
    }
  }
}

// ---------------------------------------------------------------------------
__global__ __launch_bounds__(256) void cvt_pair(const float* __restrict__ x,
                                                const float* __restrict__ y,
                                                u16* __restrict__ ox,
                                                u16* __restrict__ oy, int n4) {
  const int i = blockIdx.x * 256 + threadIdx.x;
  if (i >= n4) return;
  const float4 a = ((const float4*)x)[i];
  const float4 b = ((const float4*)y)[i];
  u16x4 oa, ob;
  oa[0] = f2bf(a.x); oa[1] = f2bf(a.y); oa[2] = f2bf(a.z); oa[3] = f2bf(a.w);
  ob[0] = f2bf(b.x); ob[1] = f2bf(b.y); ob[2] = f2bf(b.z); ob[3] = f2bf(b.w);
  ((u16x4*)ox)[i] = oa;
  ((u16x4*)oy)[i] = ob;
}

// ---------------------------------------------------------------------------
__global__ __launch_bounds__(256) void wtrans_k(const float* __restrict__ W,
                                                u16* __restrict__ WT) {
  const int tr = blockIdx.y * 64;
  const int tc = blockIdx.x * 64;
  __shared__ float T[64][65];
  const int t = threadIdx.x;
  const int r0 = t >> 4;
  const int c0 = (t & 15) * 4;
#pragma unroll
  for (int rr = 0; rr < 4; ++rr) {
    const int row = rr * 16 + r0;
    const float4 w = *(const float4*)&W[(size_t)(tr + row) * 512 + tc + c0];
    T[row][c0 + 0] = w.x; T[row][c0 + 1] = w.y;
    T[row][c0 + 2] = w.z; T[row][c0 + 3] = w.w;
  }
  __syncthreads();
#pragma unroll
  for (int rr = 0; rr < 4; ++rr) {
    const int orow = rr * 16 + r0;
    u16x4 o;
#pragma unroll
    for (int j = 0; j < 4; ++j) o[j] = f2bf(T[c0 + j][orow]);
    *(u16x4*)&WT[(size_t)(tc + orow) * 512 + tr + c0] = o;
  }
}

// ---------------------------------------------------------------------------
extern "C" void kernel_launch(void* const* d_in, const int* in_sizes, int n_in,
                              void* d_out, int out_size, void* d_ws,
                              size_t ws_size, hipStream_t stream) {
  const float* rgb = (const float*)d_in[0];
  const float* dep = (const float*)d_in[1];
  const float* Wq = (const float*)d_in[2];
  const float* bq = (const float*)d_in[3];
  const float* Wk = (const float*)d_in[4];
  const float* bk = (const float*)d_in[5];
  const float* Wv = (const float*)d_in[6];
  const float* bv = (const float*)d_in[7];
  float* out = (float*)d_out;

  const int B = 4, N = 4096, M = 4096, C = 512;
  const size_t nBNC = (size_t)B * N * C;
  const float scale = 0.044194173824159216f;  // 512^-0.5

  char* ws = (char*)d_ws;
  size_t off = 0;
  auto carve = [&](size_t bytes) -> void* {
    void* p = ws + off;
    off += (bytes + 255) & ~(size_t)255;
    return p;
  };
  u16* rgb_bf = (u16*)carve(nBNC * 2);
  u16* dep_bf = (u16*)carve(nBNC * 2);
  u16* WqT = (u16*)carve((size_t)C * C * 2);
  u16* WkT = (u16*)carve((size_t)C * C * 2);
  u16* WvT = (u16*)carve((size_t)C * C * 2);
  u16* Qb = (u16*)carve(nBNC * 2);
  u16* Kb = (u16*)carve(nBNC * 2);
  u16* Vt = (u16*)carve(nBNC * 2);
  u16* Sb = (u16*)carve((size_t)B * N * M * 2);  // 134 MB expS

  const long long strQ = (long long)N * C;  // 2,097,152
  const long long strS = (long long)N * M;  // 16,777,216
  const long long strV = (long long)C * M;  // 2,097,152

  // 0) conversions
  cvt_pair<<<8192, 256, 0, stream>>>(rgb, dep, rgb_bf, dep_bf, (int)(nBNC / 4));
  wtrans_k<<<dim3(8, 8), 256, 0, stream>>>(Wq, WqT);
  wtrans_k<<<dim3(8, 8), 256, 0, stream>>>(Wk, WkT);
  wtrans_k<<<dim3(8, 8), 256, 0, stream>>>(Wv, WvT);

  // 1) projections
  rd_gemm<1, 0><<<dim3(4, 128, 1), 256, 0, stream>>>(
      rgb_bf, WqT, bq, Qb, 16384, 512, 512, 0, 0, 0, 1.f);
  rd_gemm<1, 0><<<dim3(4, 128, 1), 256, 0, stream>>>(
      dep_bf, WkT, bk, Kb, 16384, 512, 512, 0, 0, 0, 1.f);
  rd_gemm<2, 0><<<dim3(32, 4, 4), 256, 0, stream>>>(
      WvT, dep_bf, bv, Vt, 512, 4096, 512, 0, strQ, strV, 1.f);

  // 2) expS = exp(Q K^T * scale)
  rd_gemm<0, 2><<<dim3(32, 32, 4), 256, 0, stream>>>(
      Qb, Kb, nullptr, Sb, 4096, 4096, 512, strQ, strQ, strS, scale);

  // 3) O = expS @ Vt^T / rowsum(expS)   (den in-register)
  rd_pv<<<dim3(2, 64, 4), 256, 0, stream>>>(Sb, Vt, out);
}

// Round 8
// 394.503 us; speedup vs baseline: 1.8216x; 1.8216x over previous
//
#include <hip/hip_runtime.h>
#include <hip/hip_bf16.h>
#include <stdint.h>

// CrossAttention (B=4, N=M=4096, C=512), fp32 in/out, bf16 MFMA internally.
// Round 8: VGPR-staged pipelined GEMM (hipBLASLt/AITER pattern): global
// loads go to VGPRs (coalesced, wave-private -> survive barriers), ds_write
// publishes to LDS, ONE barrier/iter drains only lgkmcnt. 3-stage pipeline:
// load(it+2) | ds_write(it+1) [waits vmcnt(N!=0)] | compute(it).
// fp32->bf16 conversion folded into projection staging (cvt_pair removed).
//   Q    = rgb @ WqT^T (+bq)       [16384x512]         pgemm 128x128 (A=f32)
//   K    = dep @ WkT^T (+bk)       [16384x512]         pgemm 128x128 (A=f32)
//   Vt   = WvT @ dep^T (+bv row)   per batch [512x4096] pgemm 128x128 (B=f32)
//   expS = exp(Q K^T / sqrt(C))    per batch [4096^2]  pgemm 128x128 OUT=exp
//   O    = (expS @ Vt^T)/rowsum    per batch [4096x512] pgemm 64x256 OUT=den

typedef unsigned short u16;
typedef __attribute__((ext_vector_type(8))) short bf16x8;
typedef __attribute__((ext_vector_type(16))) float f32x16;
typedef __attribute__((ext_vector_type(4))) unsigned short u16x4;

__device__ __forceinline__ u16 f2bf(float f) {  // RNE f32 -> bf16
  unsigned x = __float_as_uint(f);
  return (u16)((x + 0x7fffu + ((x >> 16) & 1u)) >> 16);
}
__device__ __forceinline__ unsigned pack2(float a, float b) {
  return (unsigned)f2bf(a) | ((unsigned)f2bf(b) << 16);
}
__device__ __forceinline__ float bf2f(short s) {
  return __uint_as_float((unsigned)(unsigned short)s << 16);
}

// ---------------------------------------------------------------------------
// Pipelined GEMM: C[M,N] = A[M,K]*B[N,K]^T, bf16 MFMA 32x32x16, fp32 acc.
// 256 thr / 4 waves arranged (4/WC)xWC, wave tile 64x64, BK=32.
// LDS layout (R3-verified, 0 conflicts): 64-B rows, 16-B k-chunks XOR-
// swizzled by g(r)=(r+(r>>2))&3; LDS[r][c] = global[r][c^g(r)].
// Staging: thread t loads chunk c=t+i*256 (row c>>2, global chunk
// (c&3)^g(row)) into VGPR generation ring (2 gens), ds_writes it next iter.
// AF32/BF32: that operand is fp32 in global; converted to bf16 at ds_write.
// OUT_MODE: 0 bf16, 1 fp32, 2 bf16 of exp(v*scale), 3 fp32 * 1/rowsum(A)
// (mode 3 requires WC=4: all waves share A rows; den from register rowsum).
// BIAS_MODE: 0 none, 1 bias[col], 2 bias[row].
// ---------------------------------------------------------------------------
template <int TM, int TN, int WC, bool AF32, bool BF32, int BIAS_MODE,
          int OUT_MODE, int MINW>
__global__ __launch_bounds__(256, MINW) void pgemm(
    const void* __restrict__ Av, const void* __restrict__ Bv,
    const float* __restrict__ bias, void* __restrict__ Cv, int M, int N, int K,
    long long sAb, long long sBb, long long sCb, float scale) {
  constexpr int WR = 4 / WC;
  constexpr int WROWS = TM / WR;  // 64
  constexpr int WCOLS = TN / WC;  // 64
  constexpr int CA = TM / 64;     // A 16-B chunks per thread per tile
  constexpr int CB = TN / 64;

  const int bz = blockIdx.z;
  const int bm = blockIdx.y * TM;
  const int bn = blockIdx.x * TN;
  const int tid = threadIdx.x;
  const int wave = tid >> 6, lane = tid & 63;
  const int ln31 = lane & 31, half = lane >> 5;
  const int wr = wave / WC;
  const int wc = wave % WC;
  const int gl = (ln31 + (ln31 >> 2)) & 3;

  const float* Af = (const float*)Av + (size_t)bz * sAb;
  const u16* Ab = (const u16*)Av + (size_t)bz * sAb;
  const float* Bf = (const float*)Bv + (size_t)bz * sBb;
  const u16* Bb = (const u16*)Bv + (size_t)bz * sBb;

  __shared__ u16 As[2][TM * 32];
  __shared__ u16 Bs[2][TN * 32];
  __shared__ float den_s[64];

  // chunk mapping (per-thread constants)
  int rA[CA], cA[CA], gA[CA];
#pragma unroll
  for (int i = 0; i < CA; ++i) {
    const int c = tid + i * 256;
    rA[i] = c >> 2;
    cA[i] = c & 3;
    gA[i] = (c & 3) ^ ((rA[i] + (rA[i] >> 2)) & 3);
  }
  int rB[CB], cB[CB], gB[CB];
#pragma unroll
  for (int i = 0; i < CB; ++i) {
    const int c = tid + i * 256;
    rB[i] = c >> 2;
    cB[i] = c & 3;
    gB[i] = (c & 3) ^ ((rB[i] + (rB[i] >> 2)) & 3);
  }

  // VGPR generation rings
  float4 gaf[2][AF32 ? 2 * CA : 1];
  uint4 gau[2][AF32 ? 1 : CA];
  float4 gbf[2][BF32 ? 2 * CB : 1];
  uint4 gbu[2][BF32 ? 1 : CB];

  auto loadA = [&](int s, int k0) {
#pragma unroll
    for (int i = 0; i < CA; ++i) {
      if constexpr (AF32) {
        const float* p = Af + (size_t)(bm + rA[i]) * K + k0 + gA[i] * 8;
        gaf[s][2 * i] = *(const float4*)p;
        gaf[s][2 * i + 1] = *(const float4*)(p + 4);
      } else {
        gau[s][i] =
            *(const uint4*)(Ab + (size_t)(bm + rA[i]) * K + k0 + gA[i] * 8);
      }
    }
  };
  auto loadB = [&](int s, int k0) {
#pragma unroll
    for (int i = 0; i < CB; ++i) {
      if constexpr (BF32) {
        const float* p = Bf + (size_t)(bn + rB[i]) * K + k0 + gB[i] * 8;
        gbf[s][2 * i] = *(const float4*)p;
        gbf[s][2 * i + 1] = *(const float4*)(p + 4);
      } else {
        gbu[s][i] =
            *(const uint4*)(Bb + (size_t)(bn + rB[i]) * K + k0 + gB[i] * 8);
      }
    }
  };
  auto writeA = [&](int buf, int s) {
#pragma unroll
    for (int i = 0; i < CA; ++i) {
      uint4 w;
      if constexpr (AF32) {
        const float4 x = gaf[s][2 * i], y = gaf[s][2 * i + 1];
        w.x = pack2(x.x, x.y); w.y = pack2(x.z, x.w);
        w.z = pack2(y.x, y.y); w.w = pack2(y.z, y.w);
      } else {
        w = gau[s][i];
      }
      *(uint4*)&As[buf][rA[i] * 32 + cA[i] * 8] = w;
    }
  };
  auto writeB = [&](int buf, int s) {
#pragma unroll
    for (int i = 0; i < CB; ++i) {
      uint4 w;
      if constexpr (BF32) {
        const float4 x = gbf[s][2 * i], y = gbf[s][2 * i + 1];
        w.x = pack2(x.x, x.y); w.y = pack2(x.z, x.w);
        w.z = pack2(y.x, y.y); w.w = pack2(y.z, y.w);
      } else {
        w = gbu[s][i];
      }
      *(uint4*)&Bs[buf][rB[i] * 32 + cB[i] * 8] = w;
    }
  };

  f32x16 acc[2][2] = {};
  float rsum[2] = {0.f, 0.f};
  const int niter = K >> 5;  // even (16 or 128)

  // Prologue: tiles 0,1 -> reg gens 0,1; publish tile 0.
  loadA(0, 0); loadB(0, 0);
  loadA(1, 32); loadB(1, 32);
  writeA(0, 0); writeB(0, 0);
  __syncthreads();

#define KSTEP(IT, BUF)                                                         \
  {                                                                            \
    bf16x8 af[2][2], bfv[2][2];                                                \
    _Pragma("unroll") for (int kc = 0; kc < 2; ++kc) {                         \
      const int p = ((kc * 2 + half) ^ gl) * 8;                                \
      _Pragma("unroll") for (int mt = 0; mt < 2; ++mt) af[kc][mt] =            \
          *(const bf16x8*)&As[BUF][(wr * WROWS + mt * 32 + ln31) * 32 + p];    \
      _Pragma("unroll") for (int nt = 0; nt < 2; ++nt) bfv[kc][nt] =           \
          *(const bf16x8*)&Bs[BUF][(wc * WCOLS + nt * 32 + ln31) * 32 + p];    \
    }                                                                          \
    if ((IT) + 2 < niter) {                                                    \
      loadA(BUF, ((IT) + 2) * 32);                                             \
      loadB(BUF, ((IT) + 2) * 32);                                             \
    }                                                                          \
    if ((IT) + 1 < niter) {                                                    \
      writeA(BUF ^ 1, BUF ^ 1);                                                \
      writeB(BUF ^ 1, BUF ^ 1);                                                \
    }                                                                          \
    _Pragma("unroll") for (int kc = 0; kc < 2; ++kc) {                         \
      _Pragma("unroll") for (int mt = 0; mt < 2; ++mt) {                       \
        if constexpr (OUT_MODE == 3) {                                         \
          _Pragma("unroll") for (int j = 0; j < 8; ++j) rsum[mt] +=            \
              bf2f(af[kc][mt][j]);                                             \
        }                                                                      \
        _Pragma("unroll") for (int nt = 0; nt < 2; ++nt) acc[mt][nt] =         \
            __builtin_amdgcn_mfma_f32_32x32x16_bf16(af[kc][mt], bfv[kc][nt],   \
                                                    acc[mt][nt], 0, 0, 0);     \
      }                                                                        \
    }                                                                          \
    __syncthreads();                                                           \
  }

  for (int it = 0; it < niter; it += 2) {
    KSTEP(it, 0);
    KSTEP(it + 1, 1);
  }
#undef KSTEP

  // den (mode 3): lane (ln31, half) holds rowsum of q-row mt*32+ln31 over its
  // k-half; all waves identical (WC=4 -> shared A rows); wave 0 publishes.
  if constexpr (OUT_MODE == 3) {
#pragma unroll
    for (int mt = 0; mt < 2; ++mt) rsum[mt] += __shfl_xor(rsum[mt], 32, 64);
    if (wave == 0 && half == 0) {
      den_s[ln31] = rsum[0];
      den_s[32 + ln31] = rsum[1];
    }
    __syncthreads();
  }

  // Epilogue. 32x32 C/D layout: col = lane&31, row = (r&3)+8*(r>>2)+4*half.
  const int crow0 = bm + wr * WROWS + 4 * half;
  const int ccol0 = bn + wc * WCOLS + ln31;
#pragma unroll
  for (int mt = 0; mt < 2; ++mt) {
#pragma unroll
    for (int nt = 0; nt < 2; ++nt) {
      const int col = ccol0 + nt * 32;
#pragma unroll
      for (int r = 0; r < 16; ++r) {
        const int rl = wr * WROWS + 4 * half + mt * 32 + (r & 3) + 8 * (r >> 2);
        const int row = bm + rl;
        float v = acc[mt][nt][r];
        if constexpr (BIAS_MODE == 1) v += bias[col];
        if constexpr (BIAS_MODE == 2) v += bias[row];
        const size_t idx = (size_t)bz * (size_t)sCb + (size_t)row * N + col;
        if constexpr (OUT_MODE == 0)
          ((u16*)Cv)[idx] = f2bf(v);
        else if constexpr (OUT_MODE == 1)
          ((float*)Cv)[idx] = v;
        else if constexpr (OUT_MODE == 2)
          ((u16*)Cv)[idx] = f2bf(__expf(v * scale));
        else
          ((float*)Cv)[idx] = v * (1.0f / den_s[rl]);
      }
    }
  }
}

// ---------------------------------------------------------------------------
// Transpose-convert 512x512 fp32 weight into bf16 WT[cout][cin].
// ---------------------------------------------------------------------------
__global__ __launch_bounds__(256) void wtrans_k(const float* __restrict__ W,
                                                u16* __restrict__ WT) {
  const int tr = blockIdx.y * 64;
  const int tc = blockIdx.x * 64;
  __shared__ float T[64][65];
  const int t = threadIdx.x;
  const int r0 = t >> 4;
  const int c0 = (t & 15) * 4;
#pragma unroll
  for (int rr = 0; rr < 4; ++rr) {
    const int row = rr * 16 + r0;
    const float4 w = *(const float4*)&W[(size_t)(tr + row) * 512 + tc + c0];
    T[row][c0 + 0] = w.x; T[row][c0 + 1] = w.y;
    T[row][c0 + 2] = w.z; T[row][c0 + 3] = w.w;
  }
  __syncthreads();
#pragma unroll
  for (int rr = 0; rr < 4; ++rr) {
    const int orow = rr * 16 + r0;
    u16x4 o;
#pragma unroll
    for (int j = 0; j < 4; ++j) o[j] = f2bf(T[c0 + j][orow]);
    *(u16x4*)&WT[(size_t)(tc + orow) * 512 + tr + c0] = o;
  }
}

// ---------------------------------------------------------------------------
extern "C" void kernel_launch(void* const* d_in, const int* in_sizes, int n_in,
                              void* d_out, int out_size, void* d_ws,
                              size_t ws_size, hipStream_t stream) {
  const float* rgb = (const float*)d_in[0];
  const float* dep = (const float*)d_in[1];
  const float* Wq = (const float*)d_in[2];
  const float* bq = (const float*)d_in[3];
  const float* Wk = (const float*)d_in[4];
  const float* bk = (const float*)d_in[5];
  const float* Wv = (const float*)d_in[6];
  const float* bv = (const float*)d_in[7];
  float* out = (float*)d_out;

  const int B = 4, N = 4096, M = 4096, C = 512;
  const size_t nBNC = (size_t)B * N * C;
  const float scale = 0.044194173824159216f;  // 512^-0.5

  char* ws = (char*)d_ws;
  size_t off = 0;
  auto carve = [&](size_t bytes) -> void* {
    void* p = ws + off;
    off += (bytes + 255) & ~(size_t)255;
    return p;
  };
  u16* WqT = (u16*)carve((size_t)C * C * 2);
  u16* WkT = (u16*)carve((size_t)C * C * 2);
  u16* WvT = (u16*)carve((size_t)C * C * 2);
  u16* Qb = (u16*)carve(nBNC * 2);
  u16* Kb = (u16*)carve(nBNC * 2);
  u16* Vt = (u16*)carve(nBNC * 2);
  u16* Sb = (u16*)carve((size_t)B * N * M * 2);  // 134 MB expS

  const long long strQ = (long long)N * C;  // 2,097,152
  const long long strS = (long long)N * M;  // 16,777,216
  const long long strV = (long long)C * M;  // 2,097,152

  // 0) weight transposes
  wtrans_k<<<dim3(8, 8), 256, 0, stream>>>(Wq, WqT);
  wtrans_k<<<dim3(8, 8), 256, 0, stream>>>(Wk, WkT);
  wtrans_k<<<dim3(8, 8), 256, 0, stream>>>(Wv, WvT);

  // 1) projections (fp32 operands staged+converted in-kernel)
  pgemm<128, 128, 2, true, false, 1, 0, 2><<<dim3(4, 128, 1), 256, 0, stream>>>(
      rgb, WqT, bq, Qb, 16384, 512, 512, 0, 0, 0, 1.f);
  pgemm<128, 128, 2, true, false, 1, 0, 2><<<dim3(4, 128, 1), 256, 0, stream>>>(
      dep, WkT, bk, Kb, 16384, 512, 512, 0, 0, 0, 1.f);
  pgemm<128, 128, 2, false, true, 2, 0, 2><<<dim3(32, 4, 4), 256, 0, stream>>>(
      WvT, dep, bv, Vt, 512, 4096, 512, 0, strQ, strV, 1.f);

  // 2) expS = exp(Q K^T * scale)
  pgemm<128, 128, 2, false, false, 0, 2, 3>
      <<<dim3(32, 32, 4), 256, 0, stream>>>(Qb, Kb, nullptr, Sb, 4096, 4096,
                                            512, strQ, strQ, strS, scale);

  // 3) O = expS @ Vt^T / rowsum(expS)   (den in-register, WC=4)
  pgemm<64, 256, 4, false, false, 0, 3, 2><<<dim3(2, 64, 4), 256, 0, stream>>>(
      Sb, Vt, nullptr, out, 4096, 512, 4096, strS, strV, strQ, 1.f);
}

// Round 9
// 390.201 us; speedup vs baseline: 1.8417x; 1.0110x over previous
//
#include <hip/hip_runtime.h>
#include <hip/hip_bf16.h>
#include <stdint.h>

// CrossAttention (B=4, N=M=4096, C=512), fp32 in/out, bf16 MFMA internally.
// Round 9: CK-style barrier — asm "s_waitcnt lgkmcnt(0); s_barrier" instead
// of __syncthreads(), which the HIP compiler always precedes with a FULL
// vmcnt(0) drain (kills the prefetch ring; R6==R8 proved it). Global loads
// now stay in flight across the barrier (AITER vmcnt(N!=0) pattern).
// den computed by ones-MFMA: D=A*1^T puts rowsum(A) in every acc column in
// C-layout — no shfls, no LDS publish, no VALU rowsum.
//   Q    = rgb @ WqT^T (+bq)       [16384x512]          pgemm 128x128 (A=f32)
//   K    = dep @ WkT^T (+bk)       [16384x512]          pgemm 128x128 (A=f32)
//   Vt   = WvT @ dep^T (+bv row)   per batch [512x4096] pgemm 128x128 (B=f32)
//   expS = exp(Q K^T / sqrt(C))    per batch [4096^2]   pgemm 128x128 OUT=exp
//   O    = (expS @ Vt^T)/rowsum    per batch [4096x512] pgemm 64x256 OUT=den

typedef unsigned short u16;
typedef __attribute__((ext_vector_type(8))) short bf16x8;
typedef __attribute__((ext_vector_type(16))) float f32x16;
typedef __attribute__((ext_vector_type(4))) unsigned short u16x4;

__device__ __forceinline__ u16 f2bf(float f) {  // RNE f32 -> bf16
  unsigned x = __float_as_uint(f);
  return (u16)((x + 0x7fffu + ((x >> 16) & 1u)) >> 16);
}
__device__ __forceinline__ unsigned pack2(float a, float b) {
  return (unsigned)f2bf(a) | ((unsigned)f2bf(b) << 16);
}

// Barrier that waits ONLY for LDS ops (ds_write/ds_read). Global loads in
// the VGPR prefetch ring stay in flight (unlike __syncthreads, which the
// compiler precedes with s_waitcnt vmcnt(0)).
__device__ __forceinline__ void lds_barrier() {
  asm volatile("s_waitcnt lgkmcnt(0)\n\ts_barrier" ::: "memory");
}

// ---------------------------------------------------------------------------
// Pipelined GEMM: C[M,N] = A[M,K]*B[N,K]^T, bf16 MFMA 32x32x16, fp32 acc.
// 256 thr / 4 waves arranged (4/WC)xWC, wave tile 64x64, BK=32.
// LDS (R3-verified, 0 conflicts): 64-B rows, 16-B k-chunks XOR-swizzled by
// g(r)=(r+(r>>2))&3; LDS[r][c] = global[r][c^g(r)].
// 3-stage pipeline per iter: ds_read frags(it) | load(it+2)->VGPR ring |
// ds_write(it+1) [vmcnt(N!=0)] | MFMA(it) | lds_barrier.
// AF32/BF32: operand is fp32 in global, converted at ds_write.
// OUT_MODE: 0 bf16, 1 fp32, 2 bf16 of exp(v*scale), 3 fp32 / rowsum(A)
// (mode 3: den from ones-MFMA, requires WC=4 so A rows shared by all waves).
// BIAS_MODE: 0 none, 1 bias[col], 2 bias[row].
// ---------------------------------------------------------------------------
template <int TM, int TN, int WC, bool AF32, bool BF32, int BIAS_MODE,
          int OUT_MODE, int MINW>
__global__ __launch_bounds__(256, MINW) void pgemm(
    const void* __restrict__ Av, const void* __restrict__ Bv,
    const float* __restrict__ bias, void* __restrict__ Cv, int M, int N, int K,
    long long sAb, long long sBb, long long sCb, float scale) {
  constexpr int WR = 4 / WC;
  constexpr int WROWS = TM / WR;  // 64
  constexpr int WCOLS = TN / WC;  // 64
  constexpr int CA = TM / 64;     // A 16-B chunks per thread per tile
  constexpr int CB = TN / 64;

  const int bz = blockIdx.z;
  const int bm = blockIdx.y * TM;
  const int bn = blockIdx.x * TN;
  const int tid = threadIdx.x;
  const int wave = tid >> 6, lane = tid & 63;
  const int ln31 = lane & 31, half = lane >> 5;
  const int wr = wave / WC;
  const int wc = wave % WC;
  const int gl = (ln31 + (ln31 >> 2)) & 3;

  const float* Af = (const float*)Av + (size_t)bz * sAb;
  const u16* Ab = (const u16*)Av + (size_t)bz * sAb;
  const float* Bf = (const float*)Bv + (size_t)bz * sBb;
  const u16* Bb = (const u16*)Bv + (size_t)bz * sBb;

  __shared__ u16 As[2][TM * 32];
  __shared__ u16 Bs[2][TN * 32];

  // chunk mapping (per-thread constants)
  int rA[CA], cA[CA], gA[CA];
#pragma unroll
  for (int i = 0; i < CA; ++i) {
    const int c = tid + i * 256;
    rA[i] = c >> 2;
    cA[i] = c & 3;
    gA[i] = (c & 3) ^ ((rA[i] + (rA[i] >> 2)) & 3);
  }
  int rB[CB], cB[CB], gB[CB];
#pragma unroll
  for (int i = 0; i < CB; ++i) {
    const int c = tid + i * 256;
    rB[i] = c >> 2;
    cB[i] = c & 3;
    gB[i] = (c & 3) ^ ((rB[i] + (rB[i] >> 2)) & 3);
  }

  // VGPR generation rings
  float4 gaf[2][AF32 ? 2 * CA : 1];
  uint4 gau[2][AF32 ? 1 : CA];
  float4 gbf[2][BF32 ? 2 * CB : 1];
  uint4 gbu[2][BF32 ? 1 : CB];

  auto loadA = [&](int s, int k0) {
#pragma unroll
    for (int i = 0; i < CA; ++i) {
      if constexpr (AF32) {
        const float* p = Af + (size_t)(bm + rA[i]) * K + k0 + gA[i] * 8;
        gaf[s][2 * i] = *(const float4*)p;
        gaf[s][2 * i + 1] = *(const float4*)(p + 4);
      } else {
        gau[s][i] =
            *(const uint4*)(Ab + (size_t)(bm + rA[i]) * K + k0 + gA[i] * 8);
      }
    }
  };
  auto loadB = [&](int s, int k0) {
#pragma unroll
    for (int i = 0; i < CB; ++i) {
      if constexpr (BF32) {
        const float* p = Bf + (size_t)(bn + rB[i]) * K + k0 + gB[i] * 8;
        gbf[s][2 * i] = *(const float4*)p;
        gbf[s][2 * i + 1] = *(const float4*)(p + 4);
      } else {
        gbu[s][i] =
            *(const uint4*)(Bb + (size_t)(bn + rB[i]) * K + k0 + gB[i] * 8);
      }
    }
  };
  auto writeA = [&](int buf, int s) {
#pragma unroll
    for (int i = 0; i < CA; ++i) {
      uint4 w;
      if constexpr (AF32) {
        const float4 x = gaf[s][2 * i], y = gaf[s][2 * i + 1];
        w.x = pack2(x.x, x.y); w.y = pack2(x.z, x.w);
        w.z = pack2(y.x, y.y); w.w = pack2(y.z, y.w);
      } else {
        w = gau[s][i];
      }
      *(uint4*)&As[buf][rA[i] * 32 + cA[i] * 8] = w;
    }
  };
  auto writeB = [&](int buf, int s) {
#pragma unroll
    for (int i = 0; i < CB; ++i) {
      uint4 w;
      if constexpr (BF32) {
        const float4 x = gbf[s][2 * i], y = gbf[s][2 * i + 1];
        w.x = pack2(x.x, x.y); w.y = pack2(x.z, x.w);
        w.z = pack2(y.x, y.y); w.w = pack2(y.z, y.w);
      } else {
        w = gbu[s][i];
      }
      *(uint4*)&Bs[buf][rB[i] * 32 + cB[i] * 8] = w;
    }
  };

  f32x16 acc[2][2] = {};
  f32x16 acc_d[OUT_MODE == 3 ? 2 : 1] = {};  // den accumulator (ones-MFMA)
  bf16x8 ones;
#pragma unroll
  for (int j = 0; j < 8; ++j) ones[j] = (short)0x3F80;  // bf16 1.0

  const int niter = K >> 5;  // even (16 or 128)

  // Prologue: tiles 0,1 -> reg gens 0,1; publish tile 0.
  loadA(0, 0); loadB(0, 0);
  loadA(1, 32); loadB(1, 32);
  writeA(0, 0); writeB(0, 0);
  lds_barrier();

#define KSTEP(IT, BUF)                                                         \
  {                                                                            \
    bf16x8 af[2][2], bfv[2][2];                                                \
    _Pragma("unroll") for (int kc = 0; kc < 2; ++kc) {                         \
      const int p = ((kc * 2 + half) ^ gl) * 8;                                \
      _Pragma("unroll") for (int mt = 0; mt < 2; ++mt) af[kc][mt] =            \
          *(const bf16x8*)&As[BUF][(wr * WROWS + mt * 32 + ln31) * 32 + p];    \
      _Pragma("unroll") for (int nt = 0; nt < 2; ++nt) bfv[kc][nt] =           \
          *(const bf16x8*)&Bs[BUF][(wc * WCOLS + nt * 32 + ln31) * 32 + p];    \
    }                                                                          \
    if ((IT) + 2 < niter) {                                                    \
      loadA(BUF, ((IT) + 2) * 32);                                             \
      loadB(BUF, ((IT) + 2) * 32);                                             \
    }                                                                          \
    if ((IT) + 1 < niter) {                                                    \
      writeA(BUF ^ 1, BUF ^ 1);                                                \
      writeB(BUF ^ 1, BUF ^ 1);                                                \
    }                                                                          \
    _Pragma("unroll") for (int kc = 0; kc < 2; ++kc) {                         \
      _Pragma("unroll") for (int mt = 0; mt < 2; ++mt) {                       \
        if constexpr (OUT_MODE == 3)                                           \
          acc_d[mt] = __builtin_amdgcn_mfma_f32_32x32x16_bf16(                 \
              af[kc][mt], ones, acc_d[mt], 0, 0, 0);                           \
        _Pragma("unroll") for (int nt = 0; nt < 2; ++nt) acc[mt][nt] =         \
            __builtin_amdgcn_mfma_f32_32x32x16_bf16(af[kc][mt], bfv[kc][nt],   \
                                                    acc[mt][nt], 0, 0, 0);     \
      }                                                                        \
    }                                                                          \
    lds_barrier();                                                             \
  }

  for (int it = 0; it < niter; it += 2) {
    KSTEP(it, 0);
    KSTEP(it + 1, 1);
  }
#undef KSTEP

  // Epilogue. 32x32 C/D layout: col = lane&31, row = (r&3)+8*(r>>2)+4*half.
  // Mode 3: acc_d[mt][r] holds rowsum(A) for the SAME (mt, r, half) row in
  // every column — per-lane den with zero cross-lane traffic.
  const int ccol0 = bn + wc * WCOLS + ln31;
#pragma unroll
  for (int mt = 0; mt < 2; ++mt) {
#pragma unroll
    for (int nt = 0; nt < 2; ++nt) {
      const int col = ccol0 + nt * 32;
#pragma unroll
      for (int r = 0; r < 16; ++r) {
        const int rl = wr * WROWS + 4 * half + mt * 32 + (r & 3) + 8 * (r >> 2);
        const int row = bm + rl;
        float v = acc[mt][nt][r];
        if constexpr (BIAS_MODE == 1) v += bias[col];
        if constexpr (BIAS_MODE == 2) v += bias[row];
        const size_t idx = (size_t)bz * (size_t)sCb + (size_t)row * N + col;
        if constexpr (OUT_MODE == 0)
          ((u16*)Cv)[idx] = f2bf(v);
        else if constexpr (OUT_MODE == 1)
          ((float*)Cv)[idx] = v;
        else if constexpr (OUT_MODE == 2)
          ((u16*)Cv)[idx] = f2bf(__expf(v * scale));
        else
          ((float*)Cv)[idx] = v * (1.0f / acc_d[mt][r]);
      }
    }
  }
}

// ---------------------------------------------------------------------------
// Transpose-convert 512x512 fp32 weight into bf16 WT[cout][cin].
// ---------------------------------------------------------------------------
__global__ __launch_bounds__(256) void wtrans_k(const float* __restrict__ W,
                                                u16* __restrict__ WT) {
  const int tr = blockIdx.y * 64;
  const int tc = blockIdx.x * 64;
  __shared__ float T[64][65];
  const int t = threadIdx.x;
  const int r0 = t >> 4;
  const int c0 = (t & 15) * 4;
#pragma unroll
  for (int rr = 0; rr < 4; ++rr) {
    const int row = rr * 16 + r0;
    const float4 w = *(const float4*)&W[(size_t)(tr + row) * 512 + tc + c0];
    T[row][c0 + 0] = w.x; T[row][c0 + 1] = w.y;
    T[row][c0 + 2] = w.z; T[row][c0 + 3] = w.w;
  }
  __syncthreads();
#pragma unroll
  for (int rr = 0; rr < 4; ++rr) {
    const int orow = rr * 16 + r0;
    u16x4 o;
#pragma unroll
    for (int j = 0; j < 4; ++j) o[j] = f2bf(T[c0 + j][orow]);
    *(u16x4*)&WT[(size_t)(tc + orow) * 512 + tr + c0] = o;
  }
}

// ---------------------------------------------------------------------------
extern "C" void kernel_launch(void* const* d_in, const int* in_sizes, int n_in,
                              void* d_out, int out_size, void* d_ws,
                              size_t ws_size, hipStream_t stream) {
  const float* rgb = (const float*)d_in[0];
  const float* dep = (const float*)d_in[1];
  const float* Wq = (const float*)d_in[2];
  const float* bq = (const float*)d_in[3];
  const float* Wk = (const float*)d_in[4];
  const float* bk = (const float*)d_in[5];
  const float* Wv = (const float*)d_in[6];
  const float* bv = (const float*)d_in[7];
  float* out = (float*)d_out;

  const int B = 4, N = 4096, M = 4096, C = 512;
  const size_t nBNC = (size_t)B * N * C;
  const float scale = 0.044194173824159216f;  // 512^-0.5

  char* ws = (char*)d_ws;
  size_t off = 0;
  auto carve = [&](size_t bytes) -> void* {
    void* p = ws + off;
    off += (bytes + 255) & ~(size_t)255;
    return p;
  };
  u16* WqT = (u16*)carve((size_t)C * C * 2);
  u16* WkT = (u16*)carve((size_t)C * C * 2);
  u16* WvT = (u16*)carve((size_t)C * C * 2);
  u16* Qb = (u16*)carve(nBNC * 2);
  u16* Kb = (u16*)carve(nBNC * 2);
  u16* Vt = (u16*)carve(nBNC * 2);
  u16* Sb = (u16*)carve((size_t)B * N * M * 2);  // 134 MB expS

  const long long strQ = (long long)N * C;  // 2,097,152
  const long long strS = (long long)N * M;  // 16,777,216
  const long long strV = (long long)C * M;  // 2,097,152

  // 0) weight transposes
  wtrans_k<<<dim3(8, 8), 256, 0, stream>>>(Wq, WqT);
  wtrans_k<<<dim3(8, 8), 256, 0, stream>>>(Wk, WkT);
  wtrans_k<<<dim3(8, 8), 256, 0, stream>>>(Wv, WvT);

  // 1) projections (fp32 operands staged+converted in-kernel)
  pgemm<128, 128, 2, true, false, 1, 0, 2><<<dim3(4, 128, 1), 256, 0, stream>>>(
      rgb, WqT, bq, Qb, 16384, 512, 512, 0, 0, 0, 1.f);
  pgemm<128, 128, 2, true, false, 1, 0, 2><<<dim3(4, 128, 1), 256, 0, stream>>>(
      dep, WkT, bk, Kb, 16384, 512, 512, 0, 0, 0, 1.f);
  pgemm<128, 128, 2, false, true, 2, 0, 2><<<dim3(32, 4, 4), 256, 0, stream>>>(
      WvT, dep, bv, Vt, 512, 4096, 512, 0, strQ, strV, 1.f);

  // 2) expS = exp(Q K^T * scale)
  pgemm<128, 128, 2, false, false, 0, 2, 3>
      <<<dim3(32, 32, 4), 256, 0, stream>>>(Qb, Kb, nullptr, Sb, 4096, 4096,
                                            512, strQ, strQ, strS, scale);

  // 3) O = expS @ Vt^T / rowsum(expS)   (den via ones-MFMA, WC=4)
  pgemm<64, 256, 4, false, false, 0, 3, 2><<<dim3(2, 64, 4), 256, 0, stream>>>(
      Sb, Vt, nullptr, out, 4096, 512, 4096, strS, strV, strQ, 1.f);
}